// Round 1
// baseline (6843.301 us; speedup 1.0000x reference)
//
#include <hip/hip_runtime.h>
#include <hip/hip_bf16.h>

#define E_DIM 128
#define N_NODES_C 87381

__device__ __forceinline__ float fsigmoid(float x) { return 1.0f / (1.0f + __expf(-x)); }
__device__ __forceinline__ float ftanh(float x) {
  float e = __expf(2.0f * x);
  return 1.0f - 2.0f / (e + 1.0f);
}

// Repack each 512x128 weight matrix into per-lane-contiguous layout:
// dst[((kk*32 + e4)*4 + g)*4 + x] = src[(g*128 + kk)*128 + e4*4 + x]
// so lane kk streams 128 consecutive float4 (2KB) per matrix per step.
__global__ void repack_weights(const float* __restrict__ a, const float* __restrict__ b,
                               const float* __restrict__ c, const float* __restrict__ d,
                               float* __restrict__ wr) {
  int i = blockIdx.x * 256 + threadIdx.x;
  if (i >= 4 * 65536) return;
  int mat = i >> 16;
  int r = i & 65535;
  int x = r & 3;
  int g = (r >> 2) & 3;
  int e4 = (r >> 4) & 31;
  int kk = r >> 9;
  const float* src = (mat == 0) ? a : (mat == 1) ? b : (mat == 2) ? c : d;
  wr[i] = src[(g * 128 + kk) * 128 + e4 * 4 + x];
}

// One block owns BN nodes of the level and runs the full bidirectional LSTM
// scan + linear head for them. Thread t: kk = t&127 (gate column), nsub = t>>7.
// Thread computes gate rows {kk, kk+128, kk+256, kk+384} for PP nodes.
template <int BN>
__global__ __launch_bounds__(256) void tree_scan(
    const int* __restrict__ labels, const float* __restrict__ emb,
    const float4* __restrict__ wr_ih_f, const float4* __restrict__ wr_hh_f,
    const float* __restrict__ b_ih_f, const float* __restrict__ b_hh_f,
    const float4* __restrict__ wr_ih_b, const float4* __restrict__ wr_hh_b,
    const float* __restrict__ b_ih_b, const float* __restrict__ b_hh_b,
    const float4* __restrict__ lin_w, const float* __restrict__ lin_b,
    float* __restrict__ enc, float* __restrict__ out,
    int start, int count, int T) {
  constexpr int NSUB = (BN >= 2) ? 2 : 1;
  constexpr int PP = BN / NSUB;

  __shared__ __align__(16) float sA[BN][E_DIM];   // current timestep input
  __shared__ __align__(16) float sH[BN][E_DIM];   // running h (current dir)
  __shared__ __align__(16) float sHF[BN][E_DIM];  // final forward h
  __shared__ int sLab[BN];

  const int tid = threadIdx.x;
  const int kk = tid & 127;
  const int nsub = tid >> 7;
  const bool act = (nsub < NSUB);
  const int node0 = blockIdx.x * BN;
  const int cstart = start + count;

  if (tid < BN) sLab[tid] = labels[start + node0 + tid];
  __syncthreads();

  float c_state[PP], h_new[PP];
  float4* sA4 = (float4*)sA;
  float4* sH4 = (float4*)sH;

  for (int dir = 0; dir < 2; ++dir) {
    const float4* wih = dir ? wr_ih_b : wr_ih_f;
    const float4* whh = dir ? wr_hh_b : wr_hh_f;
    const float* bih = dir ? b_ih_b : b_ih_f;
    const float* bhh = dir ? b_hh_b : b_hh_f;

    // zero h (safe: all reads of sH finished before previous dir's last barrier)
    float4 z = make_float4(0.f, 0.f, 0.f, 0.f);
    for (int idx = tid; idx < BN * 32; idx += 256) sH4[idx] = z;
#pragma unroll
    for (int m = 0; m < PP; ++m) c_state[m] = 0.f;

    const float bsum0 = bih[kk] + bhh[kk];
    const float bsum1 = bih[128 + kk] + bhh[128 + kk];
    const float bsum2 = bih[256 + kk] + bhh[256 + kk];
    const float bsum3 = bih[384 + kk] + bhh[384 + kk];

    for (int t = 0; t < T; ++t) {
      const int tseq = dir ? (T - 1 - t) : t;
      const bool isx = (T == 2) || (tseq == 0) || (tseq == T - 1);
      if (isx) {
        for (int idx = tid; idx < BN * 32; idx += 256) {
          int n = idx >> 5, e4 = idx & 31;
          sA4[idx] = ((const float4*)emb)[sLab[n] * 32 + e4];
        }
      } else {
        const int ci = tseq - 1;
        for (int idx = tid; idx < BN * 32; idx += 256) {
          int n = idx >> 5, e4 = idx & 31;
          int child = cstart + (node0 + n) * 4 + ci;
          sA4[idx] = ((const float4*)enc)[child * 32 + e4];
        }
      }
      __syncthreads();  // B1: staging + new h visible

      if (act) {
        float acc[PP][4];
#pragma unroll
        for (int m = 0; m < PP; ++m) {
          acc[m][0] = bsum0; acc[m][1] = bsum1; acc[m][2] = bsum2; acc[m][3] = bsum3;
        }
        const float4* wi = wih + kk * 128;
        const float4* wh = whh + kk * 128;
        for (int e4 = 0; e4 < 32; ++e4) {
          float4 wiv[4], whv[4];
#pragma unroll
          for (int g = 0; g < 4; ++g) {
            wiv[g] = wi[e4 * 4 + g];
            whv[g] = wh[e4 * 4 + g];
          }
#pragma unroll
          for (int m = 0; m < PP; ++m) {
            const int n = nsub + NSUB * m;
            float4 a = *(const float4*)&sA[n][e4 * 4];
            float4 h = *(const float4*)&sH[n][e4 * 4];
#pragma unroll
            for (int g = 0; g < 4; ++g) {
              acc[m][g] += a.x * wiv[g].x + a.y * wiv[g].y + a.z * wiv[g].z + a.w * wiv[g].w;
              acc[m][g] += h.x * whv[g].x + h.y * whv[g].y + h.z * whv[g].z + h.w * whv[g].w;
            }
          }
        }
#pragma unroll
        for (int m = 0; m < PP; ++m) {
          float iv = fsigmoid(acc[m][0]);
          float fv = fsigmoid(acc[m][1]);
          float gv = ftanh(acc[m][2]);
          float ov = fsigmoid(acc[m][3]);
          c_state[m] = fv * c_state[m] + iv * gv;
          h_new[m] = ov * ftanh(c_state[m]);
        }
      }
      __syncthreads();  // B2: all reads of old sA/sH complete

      if (act) {
        const bool last = (t == T - 1);
#pragma unroll
        for (int m = 0; m < PP; ++m) {
          const int n = nsub + NSUB * m;
          if (dir == 0 && last)
            sHF[n][kk] = h_new[m];
          else
            sH[n][kk] = h_new[m];
        }
      }
    }
  }
  __syncthreads();  // h_b (in sH) and h_f (in sHF) visible

  // out = tanh([h_f, h_b] @ lin_w.T + lin_b)
  if (act) {
#pragma unroll
    for (int m = 0; m < PP; ++m) {
      const int n = nsub + NSUB * m;
      float acc = lin_b[kk];
      const float4* lw = lin_w + kk * 64;  // row kk: 256 floats
#pragma unroll 8
      for (int j4 = 0; j4 < 32; ++j4) {
        float4 w4 = lw[j4];
        float4 hf = *(const float4*)&sHF[n][j4 * 4];
        acc += w4.x * hf.x + w4.y * hf.y + w4.z * hf.z + w4.w * hf.w;
      }
#pragma unroll 8
      for (int j4 = 0; j4 < 32; ++j4) {
        float4 w4 = lw[32 + j4];
        float4 hb = *(const float4*)&sH[n][j4 * 4];
        acc += w4.x * hb.x + w4.y * hb.y + w4.z * hb.z + w4.w * hb.w;
      }
      float o = ftanh(acc);
      int node = start + node0 + n;
      enc[(size_t)node * E_DIM + kk] = o;
      if (node == 0) out[kk] = o;
    }
  }
}

extern "C" void kernel_launch(void* const* d_in, const int* in_sizes, int n_in,
                              void* d_out, int out_size, void* d_ws, size_t ws_size,
                              hipStream_t stream) {
  const int* labels = (const int*)d_in[0];
  const float* emb = (const float*)d_in[1];
  const float* w_ih_f = (const float*)d_in[2];
  const float* w_hh_f = (const float*)d_in[3];
  const float* b_ih_f = (const float*)d_in[4];
  const float* b_hh_f = (const float*)d_in[5];
  const float* w_ih_b = (const float*)d_in[6];
  const float* w_hh_b = (const float*)d_in[7];
  const float* b_ih_b = (const float*)d_in[8];
  const float* b_hh_b = (const float*)d_in[9];
  const float* lin_w = (const float*)d_in[10];
  const float* lin_b = (const float*)d_in[11];
  float* out = (float*)d_out;

  float* enc = (float*)d_ws;                       // 87381*128 f32
  float* wr = enc + (size_t)N_NODES_C * E_DIM;     // 4*65536 f32 repacked weights

  repack_weights<<<1024, 256, 0, stream>>>(w_ih_f, w_hh_f, w_ih_b, w_hh_b, wr);

  const float4* wrihf = (const float4*)wr;
  const float4* wrhhf = wrihf + 16384;
  const float4* wrihb = wrihf + 32768;
  const float4* wrhhb = wrihf + 49152;
  const float4* linw4 = (const float4*)lin_w;

  static const int BN_TAB[9] = {1, 1, 2, 4, 4, 8, 8, 16, 16};

  for (int level = 8; level >= 0; --level) {
    const int start = ((1 << (2 * level)) - 1) / 3;
    const int count = 1 << (2 * level);
    const int T = (level == 8) ? 2 : 6;
    const int bn = BN_TAB[level];
    const int grid = count / bn;
#define LAUNCH_SCAN(BNV)                                                             \
  tree_scan<BNV><<<grid, 256, 0, stream>>>(labels, emb, wrihf, wrhhf, b_ih_f,        \
                                           b_hh_f, wrihb, wrhhb, b_ih_b, b_hh_b,     \
                                           linw4, lin_b, enc, out, start, count, T)
    switch (bn) {
      case 1: LAUNCH_SCAN(1); break;
      case 2: LAUNCH_SCAN(2); break;
      case 4: LAUNCH_SCAN(4); break;
      case 8: LAUNCH_SCAN(8); break;
      case 16: LAUNCH_SCAN(16); break;
    }
#undef LAUNCH_SCAN
  }
}

// Round 2
// 448.963 us; speedup vs baseline: 15.2425x; 15.2425x over previous
//
#include <hip/hip_runtime.h>
#include <hip/hip_bf16.h>

#define N_NODES_C 87381

typedef __attribute__((ext_vector_type(8))) short bf16x8;
typedef __attribute__((ext_vector_type(4))) float f32x4;

__device__ __forceinline__ ushort f2bf(float f) {
  union { float f; unsigned u; } v; v.f = f;
  unsigned u = v.u;
  return (ushort)((u + 0x7FFFu + ((u >> 16) & 1u)) >> 16);
}

__device__ __forceinline__ float fsig(float x) {
  return __builtin_amdgcn_rcpf(1.0f + __expf(-x));
}
__device__ __forceinline__ float ftnh(float x) {
  float e = __expf(2.0f * x);
  return 1.0f - 2.0f * __builtin_amdgcn_rcpf(e + 1.0f);
}

__device__ __forceinline__ f32x4 MF(bf16x8 a, bf16x8 b, f32x4 c) {
  return __builtin_amdgcn_mfma_f32_16x16x32_bf16(a, b, c, 0, 0, 0);
}

// Repack W (512x128, gate-major rows) into per-lane MFMA B-fragments:
// layout [dir][mat][wave][lane][frag=nt*4+kk][j=0..7], packed col
// pcol = (h>>4)*64 + gate*16 + (h&15) so wave w owns hidden slice
// [16w,16w+16) and lane's 4 nt-tiles = the 4 gates of ONE hidden unit.
__global__ __launch_bounds__(256) void repack(
    const float* __restrict__ wihf, const float* __restrict__ whhf,
    const float* __restrict__ wihb, const float* __restrict__ whhb,
    ushort* __restrict__ wr) {
  int i = blockIdx.x * 256 + threadIdx.x;
  if (i >= 262144) return;
  int j = i & 7;
  int fr = (i >> 3) & 15;
  int lane = (i >> 7) & 63;
  int w = (i >> 13) & 7;
  int m = (i >> 16) & 1;
  int d = (i >> 17) & 1;
  int nt = fr >> 2, kk = fr & 3;
  int pcol = w * 64 + nt * 16 + (lane & 15);
  int gate = (pcol >> 4) & 3;
  int h = ((pcol >> 6) << 4) | (pcol & 15);
  int k = kk * 32 + (lane >> 4) * 8 + j;
  const float* src = d ? (m ? whhb : wihb) : (m ? whhf : wihf);
  wr[i] = f2bf(src[(gate * 128 + h) * 128 + k]);
}

template <int NG>
__global__ __launch_bounds__(512) void tree_level(
    const int* __restrict__ labels, const float* __restrict__ emb,
    const ushort* __restrict__ wrep,
    const float* __restrict__ bihf, const float* __restrict__ bhhf,
    const float* __restrict__ bihb, const float* __restrict__ bhhb,
    const float* __restrict__ linw, const float* __restrict__ linb,
    float* __restrict__ enc, float* __restrict__ out,
    int start, int count, int T, int ngroups) {
  __shared__ __align__(16) ushort sX[2048];          // [16][128] bf16, XOR-swizzled
  __shared__ __align__(16) ushort sH[2048];          // [16][128] bf16, XOR-swizzled
  __shared__ __align__(16) ushort sHF[NG][4096];     // [16][256] bf16 per group

  const int tid = threadIdx.x;
  const int w = tid >> 6;       // wave 0..7 -> hidden slice / n-tile group
  const int l = tid & 63;
  const int hlo = l & 15;
  const int lg = l >> 4;
  const int r0 = lg * 4;        // C-fragment row base
  const int hcol = w * 16 + hlo;  // this lane's hidden unit
  const int arow = hlo;           // A-fragment M row = lane&15
  const int axswz = (arow & 7) << 3;
  const int k0base = lg * 8;

  const int cstart = start + count;
  const int g0 = blockIdx.x * NG;

  for (int dir = 0; dir < 2; ++dir) {
    // ---- load weight B-fragments into VGPRs (once per dir) ----
    bf16x8 wih[16], whh[16];
    {
      const ushort* p0 = wrep + (((dir * 2 + 0) * 8 + w) << 13) + l * 128;
      const ushort* p1 = wrep + (((dir * 2 + 1) * 8 + w) << 13) + l * 128;
#pragma unroll
      for (int f = 0; f < 16; ++f) {
        wih[f] = *(const bf16x8*)(p0 + f * 8);
        whh[f] = *(const bf16x8*)(p1 + f * 8);
      }
    }
    const float* bih = dir ? bihb : bihf;
    const float* bhh = dir ? bhhb : bhhf;
    float bs[4];
#pragma unroll
    for (int nt = 0; nt < 4; ++nt) {
      int rrow = nt * 128 + hcol;   // gate nt, hidden hcol
      bs[nt] = bih[rrow] + bhh[rrow];
    }

    for (int g = 0; g < NG; ++g) {
      if (g0 + g >= ngroups) break;   // uniform per block
      const int node0 = (g0 + g) * 16;
      f32x4 accx[4];
      float c_st[4], hn[4];

      for (int t = 0; t < T; ++t) {
        // ---- staging phase ----
        if (t == 0) {
          int row = tid >> 5, col0 = (tid & 31) * 4;
          int n = node0 + row; if (n >= count) n = count - 1;
          int lab = labels[start + n];
          float4 v = *(const float4*)(emb + lab * 128 + col0);
          ushort4 b4 = { f2bf(v.x), f2bf(v.y), f2bf(v.z), f2bf(v.w) };
          *(ushort4*)(sX + row * 128 + (col0 ^ ((row & 7) << 3))) = b4;
        } else if (t < T - 1) {
          int ci = dir ? (T - 2 - t) : (t - 1);
          int row = tid >> 5, col0 = (tid & 31) * 4;
          int n = node0 + row; if (n >= count) n = count - 1;
          size_t child = (size_t)(cstart + n * 4 + ci);
          float4 v = *(const float4*)(enc + child * 128 + col0);
          ushort4 b4 = { f2bf(v.x), f2bf(v.y), f2bf(v.z), f2bf(v.w) };
          *(ushort4*)(sX + row * 128 + (col0 ^ ((row & 7) << 3))) = b4;
        }
        if (t > 0) {
#pragma unroll
          for (int rg = 0; rg < 4; ++rg) {
            int rr = r0 + rg;
            sH[rr * 128 + (hcol ^ ((rr & 7) << 3))] = f2bf(hn[rg]);
          }
        }
        __syncthreads();   // B1: sX / sH ready

        // ---- compute phase ----
        f32x4 a4[4];
        if (t == 0) {
          bf16x8 ax[4];
#pragma unroll
          for (int kk = 0; kk < 4; ++kk)
            ax[kk] = *(const bf16x8*)(sX + arow * 128 + ((kk * 32 + k0base) ^ axswz));
#pragma unroll
          for (int nt = 0; nt < 4; ++nt) { f32x4 z = {0.f, 0.f, 0.f, 0.f}; accx[nt] = z; }
#pragma unroll
          for (int kk = 0; kk < 4; ++kk)
#pragma unroll
            for (int nt = 0; nt < 4; ++nt)
              accx[nt] = MF(ax[kk], wih[nt * 4 + kk], accx[nt]);
#pragma unroll
          for (int nt = 0; nt < 4; ++nt) {
            a4[nt] = accx[nt];
#pragma unroll
            for (int rg = 0; rg < 4; ++rg) a4[nt][rg] += bs[nt];
          }
        } else {
#pragma unroll
          for (int nt = 0; nt < 4; ++nt) {
            f32x4 z = {bs[nt], bs[nt], bs[nt], bs[nt]};
            a4[nt] = z;
          }
          if (t < T - 1) {
            bf16x8 ax[4];
#pragma unroll
            for (int kk = 0; kk < 4; ++kk)
              ax[kk] = *(const bf16x8*)(sX + arow * 128 + ((kk * 32 + k0base) ^ axswz));
#pragma unroll
            for (int kk = 0; kk < 4; ++kk)
#pragma unroll
              for (int nt = 0; nt < 4; ++nt)
                a4[nt] = MF(ax[kk], wih[nt * 4 + kk], a4[nt]);
          } else {
            // seq[T-1] == seq[0] == x : reuse cached x-side gates
#pragma unroll
            for (int nt = 0; nt < 4; ++nt)
#pragma unroll
              for (int rg = 0; rg < 4; ++rg) a4[nt][rg] += accx[nt][rg];
          }
          bf16x8 ah[4];
#pragma unroll
          for (int kk = 0; kk < 4; ++kk)
            ah[kk] = *(const bf16x8*)(sH + arow * 128 + ((kk * 32 + k0base) ^ axswz));
#pragma unroll
          for (int kk = 0; kk < 4; ++kk)
#pragma unroll
            for (int nt = 0; nt < 4; ++nt)
              a4[nt] = MF(ah[kk], whh[nt * 4 + kk], a4[nt]);
        }
        // LSTM elementwise: gates i,f,g,o are a4[0..3], all lane-local
#pragma unroll
        for (int rg = 0; rg < 4; ++rg) {
          float iv = fsig(a4[0][rg]);
          float fv = fsig(a4[1][rg]);
          float gv = ftnh(a4[2][rg]);
          float ov = fsig(a4[3][rg]);
          float c = (t == 0) ? (iv * gv) : (fv * c_st[rg] + iv * gv);
          c_st[rg] = c;
          hn[rg] = ov * ftnh(c);
        }
        __syncthreads();   // B2: everyone done reading sX/sH
      }
      // final h of this direction -> sHF[g] (cols dir*128 + h)
#pragma unroll
      for (int rg = 0; rg < 4; ++rg) {
        int rr = r0 + rg;
        int cc = dir * 128 + hcol;
        sHF[g][rr * 256 + (cc ^ ((rr & 7) << 3))] = f2bf(hn[rg]);
      }
    }
  }
  __syncthreads();   // all sHF writes visible

  // ---- head: out = tanh([hf,hb] @ lin_w^T + lin_b), wave w -> cols 16w..16w+15
  bf16x8 lw[8];
  const int e = hcol;
#pragma unroll
  for (int kk = 0; kk < 8; ++kk) {
    int k = kk * 32 + k0base;
    float4 v0 = *(const float4*)(linw + e * 256 + k);
    float4 v1 = *(const float4*)(linw + e * 256 + k + 4);
    bf16x8 b;
    b[0] = f2bf(v0.x); b[1] = f2bf(v0.y); b[2] = f2bf(v0.z); b[3] = f2bf(v0.w);
    b[4] = f2bf(v1.x); b[5] = f2bf(v1.y); b[6] = f2bf(v1.z); b[7] = f2bf(v1.w);
    lw[kk] = b;
  }
  const float lb = linb[e];
  for (int g = 0; g < NG; ++g) {
    if (g0 + g >= ngroups) break;
    const int node0 = (g0 + g) * 16;
    f32x4 a2 = {lb, lb, lb, lb};
#pragma unroll
    for (int kk = 0; kk < 8; ++kk) {
      bf16x8 ah = *(const bf16x8*)(sHF[g] + arow * 256 + ((kk * 32 + k0base) ^ axswz));
      a2 = MF(ah, lw[kk], a2);
    }
#pragma unroll
    for (int rg = 0; rg < 4; ++rg) {
      int n = node0 + r0 + rg;
      if (n < count) {
        float val = ftnh(a2[rg]);
        enc[(size_t)(start + n) * 128 + e] = val;
        if (start + n == 0) out[e] = val;
      }
    }
  }
}

extern "C" void kernel_launch(void* const* d_in, const int* in_sizes, int n_in,
                              void* d_out, int out_size, void* d_ws, size_t ws_size,
                              hipStream_t stream) {
  const int* labels = (const int*)d_in[0];
  const float* emb = (const float*)d_in[1];
  const float* w_ih_f = (const float*)d_in[2];
  const float* w_hh_f = (const float*)d_in[3];
  const float* b_ih_f = (const float*)d_in[4];
  const float* b_hh_f = (const float*)d_in[5];
  const float* w_ih_b = (const float*)d_in[6];
  const float* w_hh_b = (const float*)d_in[7];
  const float* b_ih_b = (const float*)d_in[8];
  const float* b_hh_b = (const float*)d_in[9];
  const float* lin_w = (const float*)d_in[10];
  const float* lin_b = (const float*)d_in[11];
  float* out = (float*)d_out;

  float* enc = (float*)d_ws;                                 // 87381*128 f32
  ushort* wrep = (ushort*)(enc + (size_t)N_NODES_C * 128);   // 512KB fragments

  repack<<<1024, 256, 0, stream>>>(w_ih_f, w_hh_f, w_ih_b, w_hh_b, wrep);

  for (int level = 8; level >= 0; --level) {
    const int start = ((1 << (2 * level)) - 1) / 3;
    const int count = 1 << (2 * level);
    const int T = (level == 8) ? 2 : 6;
    const int ngroups = (count + 15) >> 4;
    const int ng = (level == 8) ? 8 : (level == 7) ? 4 : 1;
    const int grid = (ngroups + ng - 1) / ng;
    if (ng == 8)
      tree_level<8><<<grid, 512, 0, stream>>>(labels, emb, wrep, b_ih_f, b_hh_f,
                                              b_ih_b, b_hh_b, lin_w, lin_b, enc,
                                              out, start, count, T, ngroups);
    else if (ng == 4)
      tree_level<4><<<grid, 512, 0, stream>>>(labels, emb, wrep, b_ih_f, b_hh_f,
                                              b_ih_b, b_hh_b, lin_w, lin_b, enc,
                                              out, start, count, T, ngroups);
    else
      tree_level<1><<<grid, 512, 0, stream>>>(labels, emb, wrep, b_ih_f, b_hh_f,
                                              b_ih_b, b_hh_b, lin_w, lin_b, enc,
                                              out, start, count, T, ngroups);
  }
}

// Round 3
// 440.218 us; speedup vs baseline: 15.5453x; 1.0199x over previous
//
#include <hip/hip_runtime.h>
#include <hip/hip_bf16.h>

#define N_NODES_C 87381

typedef __attribute__((ext_vector_type(8))) short bf16x8;
typedef __attribute__((ext_vector_type(4))) float f32x4;

__device__ __forceinline__ ushort f2bf(float f) {
  union { float f; unsigned u; } v; v.f = f;
  unsigned u = v.u;
  return (ushort)((u + 0x7FFFu + ((u >> 16) & 1u)) >> 16);
}

__device__ __forceinline__ float fsig(float x) {
  return __builtin_amdgcn_rcpf(1.0f + __expf(-x));
}
__device__ __forceinline__ float ftnh(float x) {
  float e = __expf(2.0f * x);
  return 1.0f - 2.0f * __builtin_amdgcn_rcpf(e + 1.0f);
}

__device__ __forceinline__ f32x4 MF(bf16x8 a, bf16x8 b, f32x4 c) {
  return __builtin_amdgcn_mfma_f32_16x16x32_bf16(a, b, c, 0, 0, 0);
}

// One repack kernel:
//  [0, 262144)           : gate-weight B-fragments (as round 2)
//  [262144, 393216)      : emb -> bf16
//  [393216, 425984)      : lin_w -> per-lane B-fragments
__global__ __launch_bounds__(256) void repack_all(
    const float* __restrict__ wihf, const float* __restrict__ whhf,
    const float* __restrict__ wihb, const float* __restrict__ whhb,
    const float* __restrict__ emb, const float* __restrict__ linw,
    ushort* __restrict__ wrep, ushort* __restrict__ emb_bf,
    ushort* __restrict__ lwrep) {
  int i = blockIdx.x * 256 + threadIdx.x;
  if (i < 262144) {
    int j = i & 7;
    int fr = (i >> 3) & 15;
    int lane = (i >> 7) & 63;
    int w = (i >> 13) & 7;
    int m = (i >> 16) & 1;
    int d = (i >> 17) & 1;
    int nt = fr >> 2, kk = fr & 3;
    int pcol = w * 64 + nt * 16 + (lane & 15);
    int gate = (pcol >> 4) & 3;
    int h = ((pcol >> 6) << 4) | (pcol & 15);
    int k = kk * 32 + (lane >> 4) * 8 + j;
    const float* src = d ? (m ? whhb : wihb) : (m ? whhf : wihf);
    wrep[i] = f2bf(src[(gate * 128 + h) * 128 + k]);
  } else if (i < 393216) {
    int r = i - 262144;
    emb_bf[r] = f2bf(emb[r]);
  } else if (i < 425984) {
    int r = i - 393216;
    int j = r & 7;
    int kk = (r >> 3) & 7;
    int l = (r >> 6) & 63;
    int w = (r >> 12) & 7;
    int e = w * 16 + (l & 15);
    int k = kk * 32 + (l >> 4) * 8 + j;
    lwrep[r] = f2bf(linw[e * 256 + k]);
  }
}

// 8 waves; wave w owns hidden slice [16w,16w+16) (all 4 gates of a hidden
// unit land in one lane's C-fragments). Per timestep: ONE barrier; child
// tiles double-buffered with issue-early/write-late prefetch; x-side gates
// cached in regs and reused at t=T-1.
template <int NG>
__global__ __launch_bounds__(512) void tree_level(
    const int* __restrict__ labels, const ushort* __restrict__ emb_bf,
    const ushort* __restrict__ wrep,
    const float* __restrict__ bihf, const float* __restrict__ bhhf,
    const float* __restrict__ bihb, const float* __restrict__ bhhb,
    const ushort* __restrict__ lwrep, const float* __restrict__ linb,
    ushort* __restrict__ enc, float* __restrict__ out,
    int start, int count, int T, int ngroups) {
  __shared__ __align__(16) ushort sXx[2048];     // x tile [16][128], swizzled
  __shared__ __align__(16) ushort sXc[2][2048];  // children dbuf
  __shared__ __align__(16) ushort sH[2][2048];   // h dbuf
  __shared__ __align__(16) ushort sHF[NG][2048]; // dir0 final h per group
  __shared__ int sLab[NG * 16];

  const int tid = threadIdx.x;
  const int w = tid >> 6;
  const int l = tid & 63;
  const int hlo = l & 15;
  const int lg = l >> 4;
  const int r0 = lg * 4;
  const int hcol = w * 16 + hlo;
  const int arow = hlo;
  const int axswz = (arow & 7) << 3;
  const int k0base = lg * 8;
  const int g0 = blockIdx.x * NG;

  // staging mapping: 512 threads cover a [16][128] bf16 tile, 4 elems each
  const int srow = tid >> 5;
  const int scol = (tid & 31) * 4;
  const int sdst = srow * 128 + (scol ^ ((srow & 7) << 3));

  if (tid < NG * 16) {
    int n = g0 * 16 + tid;
    if (n >= count) n = count - 1;
    sLab[tid] = labels[start + n];
  }
  const float lb = linb[hcol];
  __syncthreads();

  for (int dir = 0; dir < 2; ++dir) {
    // weight B-fragments -> regs (once per dir)
    bf16x8 wih[16], whh[16];
    {
      const ushort* p0 = wrep + (((dir * 2 + 0) * 8 + w) << 13) + l * 128;
      const ushort* p1 = wrep + (((dir * 2 + 1) * 8 + w) << 13) + l * 128;
#pragma unroll
      for (int f = 0; f < 16; ++f) {
        wih[f] = *(const bf16x8*)(p0 + f * 8);
        whh[f] = *(const bf16x8*)(p1 + f * 8);
      }
    }
    const float* bih = dir ? bihb : bihf;
    const float* bhh = dir ? bhhb : bhhf;
    float bs[4];
#pragma unroll
    for (int nt = 0; nt < 4; ++nt) bs[nt] = bih[nt * 128 + hcol] + bhh[nt * 128 + hcol];

    for (int g = 0; g < NG; ++g) {
      if (g0 + g >= ngroups) break;
      const int node0 = (g0 + g) * 16;

      // group-start staging: x tile + (T>2) child tile for step 1
      {
        int lab = sLab[g * 16 + srow];
        *(ushort4*)(sXx + sdst) = *(const ushort4*)(emb_bf + lab * 128 + scol);
        if (T > 2) {
          int n = node0 + srow;
          if (n >= count) n = count - 1;
          int ci = dir ? (T - 3) : 0;  // child index for step 1
          *(ushort4*)(sXc[0] + sdst) =
              *(const ushort4*)(enc + ((size_t)(4 * (start + n) + 1 + ci)) * 128 + scol);
        }
      }
      f32x4 accx[4];
      float c_st[4], hn[4];
      __syncthreads();  // S0

      for (int t = 0; t < T; ++t) {
        // issue prefetch for step t+1's children (hidden under compute)
        ushort4 pf;
        const bool do_pf = (t >= 1) && (t + 1 <= T - 2);
        if (do_pf) {
          int n = node0 + srow;
          if (n >= count) n = count - 1;
          int ci = dir ? (T - 3 - t) : t;  // ci(step t+1)
          pf = *(const ushort4*)(enc + ((size_t)(4 * (start + n) + 1 + ci)) * 128 + scol);
        }

        f32x4 a4[4];
        if (t == 0) {
          bf16x8 ax[4];
#pragma unroll
          for (int kk = 0; kk < 4; ++kk)
            ax[kk] = *(const bf16x8*)(sXx + arow * 128 + ((kk * 32 + k0base) ^ axswz));
#pragma unroll
          for (int nt = 0; nt < 4; ++nt) { f32x4 z = {0.f, 0.f, 0.f, 0.f}; accx[nt] = z; }
#pragma unroll
          for (int kk = 0; kk < 4; ++kk)
#pragma unroll
            for (int nt = 0; nt < 4; ++nt)
              accx[nt] = MF(ax[kk], wih[nt * 4 + kk], accx[nt]);
#pragma unroll
          for (int nt = 0; nt < 4; ++nt) {
            a4[nt] = accx[nt];
#pragma unroll
            for (int rg = 0; rg < 4; ++rg) a4[nt][rg] += bs[nt];
          }
        } else {
#pragma unroll
          for (int nt = 0; nt < 4; ++nt) {
            f32x4 z = {bs[nt], bs[nt], bs[nt], bs[nt]};
            a4[nt] = z;
          }
          if (t < T - 1) {
            bf16x8 ax[4];
#pragma unroll
            for (int kk = 0; kk < 4; ++kk)
              ax[kk] = *(const bf16x8*)(sXc[(t + 1) & 1] + arow * 128 +
                                        ((kk * 32 + k0base) ^ axswz));
#pragma unroll
            for (int kk = 0; kk < 4; ++kk)
#pragma unroll
              for (int nt = 0; nt < 4; ++nt)
                a4[nt] = MF(ax[kk], wih[nt * 4 + kk], a4[nt]);
          } else {
#pragma unroll
            for (int nt = 0; nt < 4; ++nt)
#pragma unroll
              for (int rg = 0; rg < 4; ++rg) a4[nt][rg] += accx[nt][rg];
          }
          bf16x8 ah[4];
#pragma unroll
          for (int kk = 0; kk < 4; ++kk)
            ah[kk] = *(const bf16x8*)(sH[(t + 1) & 1] + arow * 128 +
                                      ((kk * 32 + k0base) ^ axswz));
#pragma unroll
          for (int kk = 0; kk < 4; ++kk)
#pragma unroll
            for (int nt = 0; nt < 4; ++nt)
              a4[nt] = MF(ah[kk], whh[nt * 4 + kk], a4[nt]);
        }

        // lane-local LSTM elementwise
#pragma unroll
        for (int rg = 0; rg < 4; ++rg) {
          float iv = fsig(a4[0][rg]);
          float fv = fsig(a4[1][rg]);
          float gv = ftnh(a4[2][rg]);
          float ov = fsig(a4[3][rg]);
          float c = (t == 0) ? (iv * gv) : (fv * c_st[rg] + iv * gv);
          c_st[rg] = c;
          hn[rg] = ov * ftnh(c);
        }

        // write phase (other buffer than what was read)
        if (t < T - 1) {
#pragma unroll
          for (int rg = 0; rg < 4; ++rg) {
            int rr = r0 + rg;
            sH[t & 1][rr * 128 + (hcol ^ ((rr & 7) << 3))] = f2bf(hn[rg]);
          }
        } else if (dir == 0) {
#pragma unroll
          for (int rg = 0; rg < 4; ++rg) {
            int rr = r0 + rg;
            sHF[g][rr * 128 + (hcol ^ ((rr & 7) << 3))] = f2bf(hn[rg]);
          }
        } else {
#pragma unroll
          for (int rg = 0; rg < 4; ++rg) {
            int rr = r0 + rg;
            sH[1][rr * 128 + (hcol ^ ((rr & 7) << 3))] = f2bf(hn[rg]);
          }
        }
        if (do_pf) *(ushort4*)(sXc[t & 1] + sdst) = pf;
        __syncthreads();
      }

      if (dir == 1) {
        // fused head: out = tanh([hf,hb] @ lin_w^T + lin_b)
        bf16x8 lw[8];
        const ushort* lp = lwrep + (w * 64 + l) * 64;
#pragma unroll
        for (int kk = 0; kk < 8; ++kk) lw[kk] = *(const bf16x8*)(lp + kk * 8);
        f32x4 a2 = {lb, lb, lb, lb};
#pragma unroll
        for (int kk = 0; kk < 4; ++kk) {
          bf16x8 hf = *(const bf16x8*)(sHF[g] + arow * 128 + ((kk * 32 + k0base) ^ axswz));
          a2 = MF(hf, lw[kk], a2);
        }
#pragma unroll
        for (int kk = 0; kk < 4; ++kk) {
          bf16x8 hb = *(const bf16x8*)(sH[1] + arow * 128 + ((kk * 32 + k0base) ^ axswz));
          a2 = MF(hb, lw[4 + kk], a2);
        }
#pragma unroll
        for (int rg = 0; rg < 4; ++rg) {
          int n = node0 + r0 + rg;
          if (n < count) {
            float val = ftnh(a2[rg]);
            enc[(size_t)(start + n) * 128 + hcol] = f2bf(val);
            if (start + n == 0) out[hcol] = val;
          }
        }
      }
    }
  }
}

extern "C" void kernel_launch(void* const* d_in, const int* in_sizes, int n_in,
                              void* d_out, int out_size, void* d_ws, size_t ws_size,
                              hipStream_t stream) {
  const int* labels = (const int*)d_in[0];
  const float* emb = (const float*)d_in[1];
  const float* w_ih_f = (const float*)d_in[2];
  const float* w_hh_f = (const float*)d_in[3];
  const float* b_ih_f = (const float*)d_in[4];
  const float* b_hh_f = (const float*)d_in[5];
  const float* w_ih_b = (const float*)d_in[6];
  const float* w_hh_b = (const float*)d_in[7];
  const float* b_ih_b = (const float*)d_in[8];
  const float* b_hh_b = (const float*)d_in[9];
  const float* lin_w = (const float*)d_in[10];
  const float* lin_b = (const float*)d_in[11];
  float* out = (float*)d_out;

  ushort* enc = (ushort*)d_ws;                       // 87381*128 bf16
  ushort* wrep = enc + (size_t)N_NODES_C * 128;      // 262144
  ushort* emb_bf = wrep + 262144;                    // 131072
  ushort* lwrep = emb_bf + 131072;                   // 32768

  repack_all<<<1664, 256, 0, stream>>>(w_ih_f, w_hh_f, w_ih_b, w_hh_b, emb,
                                       lin_w, wrep, emb_bf, lwrep);

  for (int level = 8; level >= 0; --level) {
    const int start = ((1 << (2 * level)) - 1) / 3;
    const int count = 1 << (2 * level);
    const int T = (level == 8) ? 2 : 6;
    const int ngroups = (count + 15) >> 4;
    const int ng = (level == 8) ? 16 : (level == 7) ? 4 : 1;
    const int grid = (ngroups + ng - 1) / ng;
    if (ng == 16)
      tree_level<16><<<grid, 512, 0, stream>>>(labels, emb_bf, wrep, b_ih_f, b_hh_f,
                                               b_ih_b, b_hh_b, lwrep, lin_b, enc,
                                               out, start, count, T, ngroups);
    else if (ng == 4)
      tree_level<4><<<grid, 512, 0, stream>>>(labels, emb_bf, wrep, b_ih_f, b_hh_f,
                                              b_ih_b, b_hh_b, lwrep, lin_b, enc,
                                              out, start, count, T, ngroups);
    else
      tree_level<1><<<grid, 512, 0, stream>>>(labels, emb_bf, wrep, b_ih_f, b_hh_f,
                                              b_ih_b, b_hh_b, lwrep, lin_b, enc,
                                              out, start, count, T, ngroups);
  }
}